// Round 1
// baseline (444.551 us; speedup 1.0000x reference)
//
#include <hip/hip_runtime.h>
#include <hip/hip_bf16.h>
#include <math.h>
#include <stdint.h>

#define DIM 2048
#define NH 16
#define HD 128
#define BB 8
#define TT 1024
#define NROW (BB*TT)        // 8192
#define QKVD (DIM + 2*HD)   // 2304

typedef unsigned short u16;
typedef unsigned int u32;
typedef float f32x4 __attribute__((ext_vector_type(4)));
typedef __bf16 bf16x8 __attribute__((ext_vector_type(8)));

__device__ inline u16 f2bf(float f) {
  u32 u = __builtin_bit_cast(u32, f);
  u += 0x7FFF + ((u >> 16) & 1);   // round-to-nearest-even
  return (u16)(u >> 16);
}

__device__ inline void gload_lds16(const void* g, void* l) {
  __builtin_amdgcn_global_load_lds(
      (const __attribute__((address_space(1))) void*)g,
      (__attribute__((address_space(3))) void*)l,
      16, 0, 0);
}

// ---------------- elementwise f32 -> bf16 ----------------
__global__ void cvt_f32_bf16(const float* __restrict__ in, u16* __restrict__ out, int n4) {
  int i = blockIdx.x * blockDim.x + threadIdx.x;
  int st = gridDim.x * blockDim.x;
  for (; i < n4; i += st) {
    float4 v = reinterpret_cast<const float4*>(in)[i];
    ushort4 o;
    o.x = f2bf(v.x); o.y = f2bf(v.y); o.z = f2bf(v.z); o.w = f2bf(v.w);
    reinterpret_cast<ushort4*>(out)[i] = o;
  }
}

// ---------------- NT GEMM: C[n,m] = sum_k A[n,k]*B[m,k] + bias[m] ----------------
// A: [Nrows][K] bf16, Bm: [Mcols][K] bf16. 128x128 tile, BK=32, 4 waves.
template<bool OUT_BF16, bool WRITE_VT>
__global__ __launch_bounds__(256, 2) void gemm_nt(
    const u16* __restrict__ A, const u16* __restrict__ Bm,
    const float* __restrict__ bias, void* __restrict__ Cout,
    u16* __restrict__ vT, int K, int Mcols)
{
  __shared__ u16 As[128*32];
  __shared__ u16 Bs[128*32];
  const int tid = threadIdx.x;
  const int w = tid >> 6, l = tid & 63;
  const int wm = w >> 1, wn = w & 1;
  const int rl = l & 15, gl = l >> 4;
  const int rowBase = blockIdx.x * 128;
  const int colBase = blockIdx.y * 128;

  f32x4 acc[4][4] = {};

  for (int k0 = 0; k0 < K; k0 += 32) {
    __syncthreads();   // previous iter's ds_reads complete before overwrite
#pragma unroll
    for (int i = 0; i < 2; ++i) {
      int c = i*256 + w*64 + l;
      int r = c >> 2, kc = c & 3;
      gload_lds16(A  + (size_t)(rowBase + r)*K + k0 + kc*8, &As[(i*256 + w*64)*8]);
      gload_lds16(Bm + (size_t)(colBase + r)*K + k0 + kc*8, &Bs[(i*256 + w*64)*8]);
    }
    __syncthreads();   // drains vmcnt before LDS reads

    bf16x8 af[4], bf[4];
#pragma unroll
    for (int fm = 0; fm < 4; ++fm)
      af[fm] = *(const bf16x8*)&As[(wm*64 + fm*16 + rl)*32 + gl*8];
#pragma unroll
    for (int fn = 0; fn < 4; ++fn)
      bf[fn] = *(const bf16x8*)&Bs[(wn*64 + fn*16 + rl)*32 + gl*8];
#pragma unroll
    for (int fm = 0; fm < 4; ++fm)
#pragma unroll
      for (int fn = 0; fn < 4; ++fn)
        acc[fm][fn] = __builtin_amdgcn_mfma_f32_16x16x32_bf16(af[fm], bf[fn], acc[fm][fn], 0, 0, 0);
  }

  float bv[4];
#pragma unroll
  for (int fn = 0; fn < 4; ++fn) bv[fn] = bias[colBase + wn*64 + fn*16 + rl];

#pragma unroll
  for (int fm = 0; fm < 4; ++fm) {
#pragma unroll
    for (int fn = 0; fn < 4; ++fn) {
      const int col = colBase + wn*64 + fn*16 + rl;
#pragma unroll
      for (int r = 0; r < 4; ++r) {
        const int row = rowBase + wm*64 + fm*16 + gl*4 + r;
        float v = acc[fm][fn][r] + bv[fn];
        if (OUT_BF16) ((u16*)Cout)[(size_t)row*Mcols + col] = f2bf(v);
        else          ((float*)Cout)[(size_t)row*Mcols + col] = v;
        if (WRITE_VT) {
          if (col >= DIM + HD) {            // V columns: also store V^T[b][d][t]
            int d = col - (DIM + HD);
            int b = row >> 10, t = row & 1023;
            vT[((size_t)(b*HD + d) << 10) + t] = f2bf(v);
          }
        }
      }
    }
  }
}

// ---------------- causal MQA flash attention ----------------
// grid: (T/64, B*H). 4 waves x 16 q-rows. KV tile = 64.
__global__ __launch_bounds__(256, 2) void mqa_attn(
    const u16* __restrict__ qkv, const u16* __restrict__ vT,
    u16* __restrict__ attout)
{
  __shared__ u16 Ks[64][136];    // [s][d], pad 8 -> stride 68 dwords (2-way)
  __shared__ u16 Vts[128][72];   // [d][s], pad 8 -> stride 36 dwords (2-way)
  __shared__ u16 Ps[4][16][72];  // per-wave P tile [t][s]

  const int tid = threadIdx.x;
  const int wid = tid >> 6, l = tid & 63;
  const int rl = l & 15, gl = l >> 4;
  const int qi = blockIdx.x;
  const int b = blockIdx.y >> 4, h = blockIdx.y & 15;
  const int qrow0 = qi * 64 + wid * 16;

  // Q fragments, held in registers for the whole kernel
  bf16x8 qf[4];
  {
    const u16* qp = qkv + (size_t)(b*TT + qrow0 + rl)*QKVD + h*HD + gl*8;
#pragma unroll
    for (int kk = 0; kk < 4; ++kk) qf[kk] = *(const bf16x8*)(qp + kk*32);
  }

  f32x4 accO[8] = {};
  float mrow[4], lrow[4];
#pragma unroll
  for (int r = 0; r < 4; ++r) { mrow[r] = -INFINITY; lrow[r] = 0.f; }
  const float scale = 0.08838834764831845f;  // 1/sqrt(128)

  for (int it = 0; it <= qi; ++it) {
    const int s0 = it * 64;
    __syncthreads();
#pragma unroll
    for (int i = 0; i < 4; ++i) {
      int c = i*256 + tid;
      int s = c >> 4, dc = c & 15;
      uint4 kv = *(const uint4*)(qkv + (size_t)(b*TT + s0 + s)*QKVD + DIM + dc*8);
      *(uint4*)&Ks[s][dc*8] = kv;
      int d = c >> 3, sc2 = c & 7;
      uint4 vv = *(const uint4*)(vT + ((size_t)(b*HD + d) << 10) + s0 + sc2*8);
      *(uint4*)&Vts[d][sc2*8] = vv;
    }
    __syncthreads();

    // S = Q K^T
    f32x4 sc_[4] = {};
#pragma unroll
    for (int fs = 0; fs < 4; ++fs)
#pragma unroll
      for (int kk = 0; kk < 4; ++kk) {
        bf16x8 kf = *(const bf16x8*)&Ks[fs*16 + rl][kk*32 + gl*8];
        sc_[fs] = __builtin_amdgcn_mfma_f32_16x16x32_bf16(qf[kk], kf, sc_[fs], 0, 0, 0);
      }

    // online softmax (rows spread over regs r, cols over 16-lane group)
#pragma unroll
    for (int r = 0; r < 4; ++r) {
      const int tg = qrow0 + gl*4 + r;
      float mx = -INFINITY;
#pragma unroll
      for (int fs = 0; fs < 4; ++fs) {
        int sg = s0 + fs*16 + rl;
        float v = sc_[fs][r] * scale;
        v = (sg > tg) ? -INFINITY : v;
        sc_[fs][r] = v;
        mx = fmaxf(mx, v);
      }
#pragma unroll
      for (int off = 1; off < 16; off <<= 1) mx = fmaxf(mx, __shfl_xor(mx, off));
      float mnew = fmaxf(mrow[r], mx);
      float rr = __expf(mrow[r] - mnew);
      float psum = 0.f;
#pragma unroll
      for (int fs = 0; fs < 4; ++fs) {
        float p = __expf(sc_[fs][r] - mnew);
        psum += p;
        Ps[wid][gl*4 + r][fs*16 + rl] = f2bf(p);
      }
#pragma unroll
      for (int off = 1; off < 16; off <<= 1) psum += __shfl_xor(psum, off);
      mrow[r] = mnew;
      lrow[r] = lrow[r]*rr + psum;
#pragma unroll
      for (int fd = 0; fd < 8; ++fd) accO[fd][r] *= rr;
    }

    // O += P V  (A = P from LDS, B = V via pre-transposed Vt rows)
    bf16x8 pa[2];
#pragma unroll
    for (int kk = 0; kk < 2; ++kk)
      pa[kk] = *(const bf16x8*)&Ps[wid][rl][kk*32 + gl*8];
#pragma unroll
    for (int fd = 0; fd < 8; ++fd)
#pragma unroll
      for (int kk = 0; kk < 2; ++kk) {
        bf16x8 vf = *(const bf16x8*)&Vts[fd*16 + rl][kk*32 + gl*8];
        accO[fd] = __builtin_amdgcn_mfma_f32_16x16x32_bf16(pa[kk], vf, accO[fd], 0, 0, 0);
      }
  }

#pragma unroll
  for (int fd = 0; fd < 8; ++fd)
#pragma unroll
    for (int r = 0; r < 4; ++r) {
      int t = qrow0 + gl*4 + r;
      int d = fd*16 + rl;
      float v = accO[fd][r] / lrow[r];
      attout[(size_t)(b*TT + t)*DIM + h*HD + d] = f2bf(v);
    }
}

// ---------------- launch ----------------
extern "C" void kernel_launch(void* const* d_in, const int* in_sizes, int n_in,
                              void* d_out, int out_size, void* d_ws, size_t ws_size,
                              hipStream_t stream) {
  const float* x    = (const float*)d_in[0];
  const float* Wqkv = (const float*)d_in[1];
  const float* bqkv = (const float*)d_in[2];
  const float* Wout = (const float*)d_in[3];
  const float* bout = (const float*)d_in[4];

  char* ws = (char*)d_ws;
  u16* xb    = (u16*)(ws);                                    // 33,554,432 B (reused as attb)
  u16* wqb   = (u16*)(ws + 33554432);                         //  9,437,184 B (reused as woutb)
  u16* qkvb  = (u16*)(ws + 33554432 + 9437184);               // 37,748,736 B
  u16* vtb   = (u16*)(ws + 33554432 + 9437184 + 37748736);    //  2,097,152 B
  u16* attb  = xb;     // x_bf16 dead after GEMM1
  u16* woutb = wqb;    // Wqkv_bf16 dead after GEMM1

  cvt_f32_bf16<<<2048, 256, 0, stream>>>(x,    xb,  NROW*DIM/4);
  cvt_f32_bf16<<<2048, 256, 0, stream>>>(Wqkv, wqb, QKVD*DIM/4);

  dim3 g1(NROW/128, QKVD/128);
  gemm_nt<true, true><<<g1, 256, 0, stream>>>(xb, wqb, bqkv, qkvb, vtb, DIM, QKVD);

  cvt_f32_bf16<<<2048, 256, 0, stream>>>(Wout, woutb, DIM*DIM/4);

  dim3 ga(TT/64, BB*NH);
  mqa_attn<<<ga, 256, 0, stream>>>(qkvb, vtb, attb);

  dim3 g2(NROW/128, DIM/128);
  gemm_nt<false, false><<<g2, 256, 0, stream>>>(attb, woutb, bout, d_out, nullptr, DIM, DIM);
}

// Round 2
// 352.886 us; speedup vs baseline: 1.2598x; 1.2598x over previous
//
#include <hip/hip_runtime.h>
#include <hip/hip_bf16.h>
#include <math.h>
#include <stdint.h>

#define DIM 2048
#define NH 16
#define HD 128
#define BB 8
#define TT 1024
#define NROW (BB*TT)        // 8192
#define QKVD (DIM + 2*HD)   // 2304

typedef unsigned short u16;
typedef unsigned int u32;
typedef float f32x4 __attribute__((ext_vector_type(4)));
typedef u32 u32x4 __attribute__((ext_vector_type(4)));
typedef __bf16 bf16x8 __attribute__((ext_vector_type(8)));

__device__ inline u16 f2bf(float f) {
  u32 u = __builtin_bit_cast(u32, f);
  u += 0x7FFF + ((u >> 16) & 1);   // round-to-nearest-even
  return (u16)(u >> 16);
}

__device__ inline u32 cvt_pk_bf16(float lo, float hi) {
  u32 d;
  asm("v_cvt_pk_bf16_f32 %0, %1, %2" : "=v"(d) : "v"(lo), "v"(hi));
  return d;
}

__device__ inline void gload_lds16(const void* g, void* l) {
  __builtin_amdgcn_global_load_lds(
      (const __attribute__((address_space(1))) void*)g,
      (__attribute__((address_space(3))) void*)l,
      16, 0, 0);
}

// ---------------- elementwise f32 -> bf16 ----------------
__global__ void cvt_f32_bf16(const float* __restrict__ in, u16* __restrict__ out, int n4) {
  int i = blockIdx.x * blockDim.x + threadIdx.x;
  int st = gridDim.x * blockDim.x;
  for (; i < n4; i += st) {
    float4 v = reinterpret_cast<const float4*>(in)[i];
    ushort4 o;
    o.x = f2bf(v.x); o.y = f2bf(v.y); o.z = f2bf(v.z); o.w = f2bf(v.w);
    reinterpret_cast<ushort4*>(out)[i] = o;
  }
}

// ---------------- NT GEMM: C[n,m] = sum_k A[n,k]*B[m,k] + bias[m] ----------------
template<bool OUT_BF16, bool WRITE_VT>
__global__ __launch_bounds__(256, 2) void gemm_nt(
    const u16* __restrict__ A, const u16* __restrict__ Bm,
    const float* __restrict__ bias, void* __restrict__ Cout,
    u16* __restrict__ vT, int K, int Mcols)
{
  __shared__ u16 As[128*32];
  __shared__ u16 Bs[128*32];
  const int tid = threadIdx.x;
  const int w = tid >> 6, l = tid & 63;
  const int wm = w >> 1, wn = w & 1;
  const int rl = l & 15, gl = l >> 4;
  const int rowBase = blockIdx.x * 128;
  const int colBase = blockIdx.y * 128;

  f32x4 acc[4][4] = {};

  for (int k0 = 0; k0 < K; k0 += 32) {
    __syncthreads();
#pragma unroll
    for (int i = 0; i < 2; ++i) {
      int c = i*256 + w*64 + l;
      int r = c >> 2, kc = c & 3;
      gload_lds16(A  + (size_t)(rowBase + r)*K + k0 + kc*8, &As[(i*256 + w*64)*8]);
      gload_lds16(Bm + (size_t)(colBase + r)*K + k0 + kc*8, &Bs[(i*256 + w*64)*8]);
    }
    __syncthreads();

    bf16x8 af[4], bf[4];
#pragma unroll
    for (int fm = 0; fm < 4; ++fm)
      af[fm] = *(const bf16x8*)&As[(wm*64 + fm*16 + rl)*32 + gl*8];
#pragma unroll
    for (int fn = 0; fn < 4; ++fn)
      bf[fn] = *(const bf16x8*)&Bs[(wn*64 + fn*16 + rl)*32 + gl*8];
#pragma unroll
    for (int fm = 0; fm < 4; ++fm)
#pragma unroll
      for (int fn = 0; fn < 4; ++fn)
        acc[fm][fn] = __builtin_amdgcn_mfma_f32_16x16x32_bf16(af[fm], bf[fn], acc[fm][fn], 0, 0, 0);
  }

  float bv[4];
#pragma unroll
  for (int fn = 0; fn < 4; ++fn) bv[fn] = bias[colBase + wn*64 + fn*16 + rl];

#pragma unroll
  for (int fm = 0; fm < 4; ++fm) {
#pragma unroll
    for (int fn = 0; fn < 4; ++fn) {
      const int col = colBase + wn*64 + fn*16 + rl;
#pragma unroll
      for (int r = 0; r < 4; ++r) {
        const int row = rowBase + wm*64 + fm*16 + gl*4 + r;
        float v = acc[fm][fn][r] + bv[fn];
        if (OUT_BF16) ((u16*)Cout)[(size_t)row*Mcols + col] = f2bf(v);
        else          ((float*)Cout)[(size_t)row*Mcols + col] = v;
        if (WRITE_VT) {
          if (col >= DIM + HD) {
            int d = col - (DIM + HD);
            int b = row >> 10, t = row & 1023;
            vT[((size_t)(b*HD + d) << 10) + t] = f2bf(v);
          }
        }
      }
    }
  }
}

// ---------------- causal MQA flash attention (swapped-QK, pipelined) ----------------
// grid: (T/64, B*H). 4 waves x 16 q-rows. KV tile = 64, double-buffered.
__global__ __launch_bounds__(256, 2) void mqa_attn(
    const u16* __restrict__ qkv, const u16* __restrict__ vT,
    u16* __restrict__ attout)
{
  // [buf] { K: 64s x 128d bf16 (16KB, XOR-swizzled) | V^T: 128d x 64s bf16 (16KB, swizzled) }
  __shared__ char lds[65536];

  const int tid = threadIdx.x;
  const int wid = tid >> 6, l = tid & 63;
  const int rl = l & 15, gl = l >> 4;
  const int qi = blockIdx.x;
  const int b = blockIdx.y >> 4, h = blockIdx.y & 15;
  const int qrow0 = qi*64 + wid*16;
  const float scale = 0.08838834764831845f;  // 1/sqrt(128)

  const u16* kbase = qkv + (size_t)b*TT*QKVD + DIM;
  const u16* vbase = vT + ((size_t)b*HD << 10);

  // stage one KV tile: 8 x global_load_lds (16B/lane) per wave; LDS linear dest,
  // inverse-swizzled global source (m173 pattern)
  auto STAGE = [&](int buf, int s0) {
    char* kl = lds + buf*32768;
    char* vl = kl + 16384;
#pragma unroll
    for (int i = 0; i < 4; ++i) {
      int L = wid*4096 + i*1024 + l*16;
      int s = L >> 8, kb = (L & 255) ^ ((s & 7) << 4);
      gload_lds16(kbase + (size_t)(s0 + s)*QKVD + (kb >> 1), kl + wid*4096 + i*1024);
      int d = L >> 7, sb = (L & 127) ^ ((d & 7) << 4);
      gload_lds16(vbase + ((size_t)d << 10) + s0 + (sb >> 1), vl + wid*4096 + i*1024);
    }
  };

  STAGE(0, 0);
  asm volatile("" ::: "memory");   // keep qf loads AFTER stage0 issue (vmcnt ordering)

  // Q fragments (B-operand: col=t=rl, k=d)
  bf16x8 qf[4];
  {
    const u16* qp = qkv + (size_t)(b*TT + qrow0 + rl)*QKVD + h*HD + gl*8;
#pragma unroll
    for (int kk = 0; kk < 4; ++kk) qf[kk] = *(const bf16x8*)(qp + kk*32);
  }

  f32x4 accO[8] = {};
  float mrow = -INFINITY, lrow = 0.f;
  const int tg = qrow0 + rl;                       // this lane's q-row
  const int addrA = (((gl & 1) * 2) * 16 + rl) * 4;  // bpermute byte addrs
  const int addrB = addrA + 64;
  const bool hiSel = (gl >= 2);

  for (int it = 0; it <= qi; ++it) {
    if (it < qi) {
      STAGE((it + 1) & 1, (it + 1) << 6);
      asm volatile("s_waitcnt vmcnt(8)" ::: "memory");  // current tile done, next in flight
    } else {
      asm volatile("s_waitcnt vmcnt(0)" ::: "memory");
    }
    __builtin_amdgcn_s_barrier();

    const char* kl = lds + (it & 1)*32768;
    const char* vl = kl + 16384;
    const int s0 = it << 6;

    // S^T = mfma(K, Q): sc[fs][r] = S^T[s = fs*16 + gl*4 + r][t = rl]
    f32x4 sc[4] = {};
    __builtin_amdgcn_s_setprio(1);
#pragma unroll
    for (int fs = 0; fs < 4; ++fs) {
      const int s = fs*16 + rl;
#pragma unroll
      for (int kkd = 0; kkd < 4; ++kkd) {
        bf16x8 kf = *(const bf16x8*)(kl + ((s*256 + kkd*64 + gl*16) ^ ((s & 7) << 4)));
        sc[fs] = __builtin_amdgcn_mfma_f32_16x16x32_bf16(kf, qf[kkd], sc[fs], 0, 0, 0);
      }
    }
    __builtin_amdgcn_s_setprio(0);

    // online softmax — t is lane-local: in-lane reduce + 2 shfl_xor
    float mx = -INFINITY;
#pragma unroll
    for (int fs = 0; fs < 4; ++fs)
#pragma unroll
      for (int r = 0; r < 4; ++r) {
        int sg = s0 + fs*16 + gl*4 + r;
        float v = sc[fs][r] * scale;
        v = (sg > tg) ? -INFINITY : v;
        sc[fs][r] = v;
        mx = fmaxf(mx, v);
      }
    mx = fmaxf(mx, __shfl_xor(mx, 16));
    mx = fmaxf(mx, __shfl_xor(mx, 32));
    float mnew = fmaxf(mrow, mx);
    float rr = __expf(mrow - mnew);
    float ps = 0.f;
#pragma unroll
    for (int fs = 0; fs < 4; ++fs)
#pragma unroll
      for (int r = 0; r < 4; ++r) {
        float p = __expf(sc[fs][r] - mnew);
        sc[fs][r] = p;
        ps += p;
      }
    ps += __shfl_xor(ps, 16);
    ps += __shfl_xor(ps, 32);
    mrow = mnew;
    lrow = lrow * rr + ps;
#pragma unroll
    for (int fd = 0; fd < 8; ++fd)
#pragma unroll
      for (int r = 0; r < 4; ++r) accO[fd][r] *= rr;

    // pack P^T to bf16 pairs, redistribute into PV B-fragments via bpermute
    u32 pw[4][2];
#pragma unroll
    for (int fs = 0; fs < 4; ++fs) {
      pw[fs][0] = cvt_pk_bf16(sc[fs][0], sc[fs][1]);
      pw[fs][1] = cvt_pk_bf16(sc[fs][2], sc[fs][3]);
    }
    u32x4 bw[2];
#pragma unroll
    for (int kk = 0; kk < 2; ++kk)
#pragma unroll
      for (int w = 0; w < 4; ++w) {
        int addr = (w < 2) ? addrA : addrB;
        u32 lo = __builtin_amdgcn_ds_bpermute(addr, (int)pw[2*kk + 0][w & 1]);
        u32 hi = __builtin_amdgcn_ds_bpermute(addr, (int)pw[2*kk + 1][w & 1]);
        bw[kk][w] = hiSel ? hi : lo;
      }

    // O^T += V^T * P^T : accO[fd][r] = O^T[d = fd*16 + gl*4 + r][t = rl]
    __builtin_amdgcn_s_setprio(1);
#pragma unroll
    for (int kk = 0; kk < 2; ++kk) {
      bf16x8 pb = __builtin_bit_cast(bf16x8, bw[kk]);
#pragma unroll
      for (int fd = 0; fd < 8; ++fd) {
        const int d = fd*16 + rl;
        bf16x8 vf = *(const bf16x8*)(vl + ((d*128 + kk*64 + gl*16) ^ ((d & 7) << 4)));
        accO[fd] = __builtin_amdgcn_mfma_f32_16x16x32_bf16(vf, pb, accO[fd], 0, 0, 0);
      }
    }
    __builtin_amdgcn_s_setprio(0);

    __builtin_amdgcn_s_barrier();   // everyone done reading buf[it&1] before overwrite
  }

  const float inv = 1.0f / lrow;
  u16* outp = attout + (size_t)(b*TT + tg)*DIM + h*HD;
#pragma unroll
  for (int fd = 0; fd < 8; ++fd) {
    ushort4 o;
    o.x = f2bf(accO[fd][0] * inv);
    o.y = f2bf(accO[fd][1] * inv);
    o.z = f2bf(accO[fd][2] * inv);
    o.w = f2bf(accO[fd][3] * inv);
    *(ushort4*)(outp + fd*16 + gl*4) = o;
  }
}

// ---------------- launch ----------------
extern "C" void kernel_launch(void* const* d_in, const int* in_sizes, int n_in,
                              void* d_out, int out_size, void* d_ws, size_t ws_size,
                              hipStream_t stream) {
  const float* x    = (const float*)d_in[0];
  const float* Wqkv = (const float*)d_in[1];
  const float* bqkv = (const float*)d_in[2];
  const float* Wout = (const float*)d_in[3];
  const float* bout = (const float*)d_in[4];

  char* ws = (char*)d_ws;
  u16* xb    = (u16*)(ws);
  u16* wqb   = (u16*)(ws + 33554432);
  u16* qkvb  = (u16*)(ws + 33554432 + 9437184);
  u16* vtb   = (u16*)(ws + 33554432 + 9437184 + 37748736);
  u16* attb  = xb;     // x_bf16 dead after GEMM1
  u16* woutb = wqb;    // Wqkv_bf16 dead after GEMM1

  cvt_f32_bf16<<<2048, 256, 0, stream>>>(x,    xb,  NROW*DIM/4);
  cvt_f32_bf16<<<2048, 256, 0, stream>>>(Wqkv, wqb, QKVD*DIM/4);

  dim3 g1(NROW/128, QKVD/128);
  gemm_nt<true, true><<<g1, 256, 0, stream>>>(xb, wqb, bqkv, qkvb, vtb, DIM, QKVD);

  cvt_f32_bf16<<<2048, 256, 0, stream>>>(Wout, woutb, DIM*DIM/4);

  dim3 ga(TT/64, BB*NH);
  mqa_attn<<<ga, 256, 0, stream>>>(qkvb, vtb, attb);

  dim3 g2(NROW/128, DIM/128);
  gemm_nt<false, false><<<g2, 256, 0, stream>>>(attb, woutb, bout, d_out, nullptr, DIM, DIM);
}

// Round 3
// 325.495 us; speedup vs baseline: 1.3658x; 1.0842x over previous
//
#include <hip/hip_runtime.h>
#include <hip/hip_bf16.h>
#include <math.h>
#include <stdint.h>

#define DIM 2048
#define NH 16
#define HD 128
#define BB 8
#define TT 1024
#define NROW (BB*TT)        // 8192
#define QKVD (DIM + 2*HD)   // 2304

typedef unsigned short u16;
typedef unsigned int u32;
typedef float f32x4 __attribute__((ext_vector_type(4)));
typedef u32 u32x4 __attribute__((ext_vector_type(4)));
typedef __bf16 bf16x8 __attribute__((ext_vector_type(8)));

// 1/sqrt(128) * log2(e): Q pre-scaled so softmax runs in exp2 domain
#define QSCALE_LOG2E (0.08838834764831845f * 1.4426950408889634f)

__device__ inline u16 f2bf(float f) {
  u32 u = __builtin_bit_cast(u32, f);
  u += 0x7FFF + ((u >> 16) & 1);   // round-to-nearest-even
  return (u16)(u >> 16);
}

__device__ inline u32 cvt_pk_bf16(float lo, float hi) {
  u32 d;
  asm("v_cvt_pk_bf16_f32 %0, %1, %2" : "=v"(d) : "v"(lo), "v"(hi));
  return d;
}

__device__ inline void gload_lds16(const void* g, void* l) {
  __builtin_amdgcn_global_load_lds(
      (const __attribute__((address_space(1))) void*)g,
      (__attribute__((address_space(3))) void*)l,
      16, 0, 0);
}

// ---------------- elementwise f32 -> bf16 ----------------
__global__ void cvt_f32_bf16(const float* __restrict__ in, u16* __restrict__ out, int n4) {
  int i = blockIdx.x * blockDim.x + threadIdx.x;
  int st = gridDim.x * blockDim.x;
  for (; i < n4; i += st) {
    float4 v = reinterpret_cast<const float4*>(in)[i];
    ushort4 o;
    o.x = f2bf(v.x); o.y = f2bf(v.y); o.z = f2bf(v.z); o.w = f2bf(v.w);
    reinterpret_cast<ushort4*>(out)[i] = o;
  }
}

// ---------------- NT GEMM: C[n,m] = sum_k A[n,k]*B[m,k] + bias[m] ----------------
template<bool OUT_BF16, bool WRITE_VT>
__global__ __launch_bounds__(256, 2) void gemm_nt(
    const u16* __restrict__ A, const u16* __restrict__ Bm,
    const float* __restrict__ bias, void* __restrict__ Cout,
    u16* __restrict__ vT, int K, int Mcols)
{
  __shared__ u16 As[128*32];
  __shared__ u16 Bs[128*32];
  const int tid = threadIdx.x;
  const int w = tid >> 6, l = tid & 63;
  const int wm = w >> 1, wn = w & 1;
  const int rl = l & 15, gl = l >> 4;
  const int rowBase = blockIdx.x * 128;
  const int colBase = blockIdx.y * 128;

  f32x4 acc[4][4] = {};

  for (int k0 = 0; k0 < K; k0 += 32) {
    __syncthreads();
#pragma unroll
    for (int i = 0; i < 2; ++i) {
      int c = i*256 + w*64 + l;
      int r = c >> 2, kc = c & 3;
      gload_lds16(A  + (size_t)(rowBase + r)*K + k0 + kc*8, &As[(i*256 + w*64)*8]);
      gload_lds16(Bm + (size_t)(colBase + r)*K + k0 + kc*8, &Bs[(i*256 + w*64)*8]);
    }
    __syncthreads();

    bf16x8 af[4], bf[4];
#pragma unroll
    for (int fm = 0; fm < 4; ++fm)
      af[fm] = *(const bf16x8*)&As[(wm*64 + fm*16 + rl)*32 + gl*8];
#pragma unroll
    for (int fn = 0; fn < 4; ++fn)
      bf[fn] = *(const bf16x8*)&Bs[(wn*64 + fn*16 + rl)*32 + gl*8];
#pragma unroll
    for (int fm = 0; fm < 4; ++fm)
#pragma unroll
      for (int fn = 0; fn < 4; ++fn)
        acc[fm][fn] = __builtin_amdgcn_mfma_f32_16x16x32_bf16(af[fm], bf[fn], acc[fm][fn], 0, 0, 0);
  }

  float bv[4];
#pragma unroll
  for (int fn = 0; fn < 4; ++fn) bv[fn] = bias[colBase + wn*64 + fn*16 + rl];

#pragma unroll
  for (int fm = 0; fm < 4; ++fm) {
#pragma unroll
    for (int fn = 0; fn < 4; ++fn) {
      const int col = colBase + wn*64 + fn*16 + rl;
#pragma unroll
      for (int r = 0; r < 4; ++r) {
        const int row = rowBase + wm*64 + fm*16 + gl*4 + r;
        float v = acc[fm][fn][r] + bv[fn];
        if (WRITE_VT && col >= DIM + HD) {   // V columns: also store V^T[b][d][t]
          int d = col - (DIM + HD);
          int b = row >> 10, t = row & 1023;
          vT[((size_t)(b*HD + d) << 10) + t] = f2bf(v);
        }
        float vs = (WRITE_VT && col < DIM) ? v * QSCALE_LOG2E : v;  // pre-scale Q
        if (OUT_BF16) ((u16*)Cout)[(size_t)row*Mcols + col] = f2bf(vs);
        else          ((float*)Cout)[(size_t)row*Mcols + col] = vs;
      }
    }
  }
}

// ---------------- causal MQA flash attention ----------------
// grid: (T/128, B*H). 8 waves x 16 q-rows = 128 q-rows/block. KV tile = 64, dbuf.
__global__ __launch_bounds__(512, 4) void mqa_attn(
    const u16* __restrict__ qkv, const u16* __restrict__ vT,
    u16* __restrict__ attout)
{
  // [buf] { K: 64s x 128d bf16 (16KB, XOR-swizzled) | V^T: 128d x 64s bf16 (16KB, swizzled) }
  __shared__ char lds[65536];

  const int tid = threadIdx.x;
  const int wid = tid >> 6, l = tid & 63;
  const int rl = l & 15, gl = l >> 4;
  const int qb = (int)gridDim.x - 1 - (int)blockIdx.x;  // heavy blocks dispatch first
  const int b = blockIdx.y >> 4, h = blockIdx.y & 15;
  const int qrow0 = qb*128 + wid*16;
  const int diag = qrow0 >> 6;     // this wave's diagonal KV-tile index
  const int itmax = 2*qb + 1;

  const u16* kbase = qkv + (size_t)b*TT*QKVD + DIM;
  const u16* vbase = vT + ((size_t)b*HD << 10);

  // stage one KV tile: 512 threads x 16B x 2 rounds each for K and V.
  // LDS linear dest, inverse-swizzled global source (m173 pattern).
  auto STAGE = [&](int buf, int s0) {
    char* kl = lds + buf*32768;
    char* vl = kl + 16384;
#pragma unroll
    for (int i = 0; i < 2; ++i) {
      int L = (i*8 + wid)*1024 + l*16;
      int s = L >> 8, kb = (L & 255) ^ ((s & 7) << 4);
      gload_lds16(kbase + (size_t)(s0 + s)*QKVD + (kb >> 1), kl + (i*8 + wid)*1024);
      int d = L >> 7, sb = (L & 127) ^ ((d & 7) << 4);
      gload_lds16(vbase + ((size_t)d << 10) + s0 + (sb >> 1), vl + (i*8 + wid)*1024);
    }
  };

  STAGE(0, 0);
  asm volatile("" ::: "memory");

  // Q fragments (B-operand: col=t=rl, k=d); Q already scaled by 1/sqrt(hd)*log2e
  bf16x8 qf[4];
  {
    const u16* qp = qkv + (size_t)(b*TT + qrow0 + rl)*QKVD + h*HD + gl*8;
#pragma unroll
    for (int kk = 0; kk < 4; ++kk) qf[kk] = *(const bf16x8*)(qp + kk*32);
  }

  f32x4 accO[8] = {};
  float mrow = -INFINITY, lrow = 0.f;
  const int tg = qrow0 + rl;                         // this lane's q-row
  const int addrA = (((gl & 1) * 2) * 16 + rl) * 4;  // bpermute byte addrs
  const int addrB = addrA + 64;
  const bool hiSel = (gl >= 2);

  for (int it = 0; it <= itmax; ++it) {
    if (it < itmax) {
      STAGE((it + 1) & 1, (it + 1) << 6);
      asm volatile("s_waitcnt vmcnt(4)" ::: "memory");  // current tile done, next in flight
    } else {
      asm volatile("s_waitcnt vmcnt(0)" ::: "memory");
    }
    __builtin_amdgcn_s_barrier();

    if (it <= diag) {   // wave-uniform: skip fully-future tiles (still stage+barrier)
      const char* kl = lds + (it & 1)*32768;
      const char* vl = kl + 16384;

      // S^T = mfma(K, Q): sc[fs][r] = S^T[s = fs*16 + gl*4 + r][t = rl], exp2 domain
      f32x4 sc[4] = {};
      __builtin_amdgcn_s_setprio(1);
#pragma unroll
      for (int fs = 0; fs < 4; ++fs) {
        const int s = fs*16 + rl;
#pragma unroll
        for (int kkd = 0; kkd < 4; ++kkd) {
          bf16x8 kf = *(const bf16x8*)(kl + ((s*256 + kkd*64 + gl*16) ^ ((s & 7) << 4)));
          sc[fs] = __builtin_amdgcn_mfma_f32_16x16x32_bf16(kf, qf[kkd], sc[fs], 0, 0, 0);
        }
      }
      __builtin_amdgcn_s_setprio(0);

      // causal mask only on the diagonal tile (wave-uniform branch)
      if (it == diag) {
        const int s0 = it << 6;
#pragma unroll
        for (int fs = 0; fs < 4; ++fs)
#pragma unroll
          for (int r = 0; r < 4; ++r) {
            int sg = s0 + fs*16 + gl*4 + r;
            if (sg > tg) sc[fs][r] = -INFINITY;
          }
      }

      // tile max (depth-4 tree + 2 shfl)
      float mx = -INFINITY;
#pragma unroll
      for (int fs = 0; fs < 4; ++fs)
        mx = fmaxf(mx, fmaxf(fmaxf(sc[fs][0], sc[fs][1]), fmaxf(sc[fs][2], sc[fs][3])));
      mx = fmaxf(mx, __shfl_xor(mx, 16));
      mx = fmaxf(mx, __shfl_xor(mx, 32));

      // defer-max: rescale only if max grew by > 8 (exp2 domain -> P <= 256)
      if (!__all(mx <= mrow + 8.f)) {
        float mnew = fmaxf(mrow, mx);
        float rr = __builtin_amdgcn_exp2f(mrow - mnew);
#pragma unroll
        for (int fd = 0; fd < 8; ++fd)
#pragma unroll
          for (int r = 0; r < 4; ++r) accO[fd][r] *= rr;
        lrow *= rr;
        mrow = mnew;
      }

      float ps = 0.f;
#pragma unroll
      for (int fs = 0; fs < 4; ++fs)
#pragma unroll
        for (int r = 0; r < 4; ++r) {
          float p = __builtin_amdgcn_exp2f(sc[fs][r] - mrow);
          sc[fs][r] = p;
          ps += p;
        }
      ps += __shfl_xor(ps, 16);
      ps += __shfl_xor(ps, 32);
      lrow += ps;

      // pack P^T to bf16 pairs, redistribute into PV B-fragments via bpermute
      u32 pw[4][2];
#pragma unroll
      for (int fs = 0; fs < 4; ++fs) {
        pw[fs][0] = cvt_pk_bf16(sc[fs][0], sc[fs][1]);
        pw[fs][1] = cvt_pk_bf16(sc[fs][2], sc[fs][3]);
      }
      u32x4 bw[2];
#pragma unroll
      for (int kk = 0; kk < 2; ++kk)
#pragma unroll
        for (int w = 0; w < 4; ++w) {
          int addr = (w < 2) ? addrA : addrB;
          u32 lo = __builtin_amdgcn_ds_bpermute(addr, (int)pw[2*kk + 0][w & 1]);
          u32 hi = __builtin_amdgcn_ds_bpermute(addr, (int)pw[2*kk + 1][w & 1]);
          bw[kk][w] = hiSel ? hi : lo;
        }

      // O^T += V^T * P^T : accO[fd][r] = O^T[d = fd*16 + gl*4 + r][t = rl]
      __builtin_amdgcn_s_setprio(1);
#pragma unroll
      for (int kk = 0; kk < 2; ++kk) {
        bf16x8 pb = __builtin_bit_cast(bf16x8, bw[kk]);
#pragma unroll
        for (int fd = 0; fd < 8; ++fd) {
          const int d = fd*16 + rl;
          bf16x8 vf = *(const bf16x8*)(vl + ((d*128 + kk*64 + gl*16) ^ ((d & 7) << 4)));
          accO[fd] = __builtin_amdgcn_mfma_f32_16x16x32_bf16(vf, pb, accO[fd], 0, 0, 0);
        }
      }
      __builtin_amdgcn_s_setprio(0);
    }

    __builtin_amdgcn_s_barrier();   // all waves done reading buf[it&1] before overwrite
  }

  const float inv = 1.0f / lrow;
  u16* outp = attout + (size_t)(b*TT + tg)*DIM + h*HD;
#pragma unroll
  for (int fd = 0; fd < 8; ++fd) {
    ushort4 o;
    o.x = f2bf(accO[fd][0] * inv);
    o.y = f2bf(accO[fd][1] * inv);
    o.z = f2bf(accO[fd][2] * inv);
    o.w = f2bf(accO[fd][3] * inv);
    *(ushort4*)(outp + fd*16 + gl*4) = o;
  }
}

// ---------------- launch ----------------
extern "C" void kernel_launch(void* const* d_in, const int* in_sizes, int n_in,
                              void* d_out, int out_size, void* d_ws, size_t ws_size,
                              hipStream_t stream) {
  const float* x    = (const float*)d_in[0];
  const float* Wqkv = (const float*)d_in[1];
  const float* bqkv = (const float*)d_in[2];
  const float* Wout = (const float*)d_in[3];
  const float* bout = (const float*)d_in[4];

  char* ws = (char*)d_ws;
  u16* xb    = (u16*)(ws);
  u16* wqb   = (u16*)(ws + 33554432);
  u16* qkvb  = (u16*)(ws + 33554432 + 9437184);
  u16* vtb   = (u16*)(ws + 33554432 + 9437184 + 37748736);
  u16* attb  = xb;     // x_bf16 dead after GEMM1
  u16* woutb = wqb;    // Wqkv_bf16 dead after GEMM1

  cvt_f32_bf16<<<2048, 256, 0, stream>>>(x,    xb,  NROW*DIM/4);
  cvt_f32_bf16<<<2048, 256, 0, stream>>>(Wqkv, wqb, QKVD*DIM/4);

  dim3 g1(NROW/128, QKVD/128);
  gemm_nt<true, true><<<g1, 256, 0, stream>>>(xb, wqb, bqkv, qkvb, vtb, DIM, QKVD);

  cvt_f32_bf16<<<2048, 256, 0, stream>>>(Wout, woutb, DIM*DIM/4);

  dim3 ga(TT/128, BB*NH);
  mqa_attn<<<ga, 512, 0, stream>>>(qkvb, vtb, attb);

  dim3 g2(NROW/128, DIM/128);
  gemm_nt<false, false><<<g2, 256, 0, stream>>>(attb, woutb, bout, d_out, nullptr, DIM, DIM);
}

// Round 6
// 305.936 us; speedup vs baseline: 1.4531x; 1.0639x over previous
//
#include <hip/hip_runtime.h>
#include <hip/hip_bf16.h>
#include <math.h>
#include <stdint.h>

#define DIM 2048
#define NH 16
#define HD 128
#define BB 8
#define TT 1024
#define NROW (BB*TT)        // 8192
#define QKVD (DIM + 2*HD)   // 2304

typedef unsigned short u16;
typedef unsigned int u32;
typedef float f32x4 __attribute__((ext_vector_type(4)));
typedef u32 u32x4 __attribute__((ext_vector_type(4)));
typedef __bf16 bf16x8 __attribute__((ext_vector_type(8)));

// 1/sqrt(128) * log2(e): Q pre-scaled so softmax runs in exp2 domain
#define QSCALE_LOG2E (0.08838834764831845f * 1.4426950408889634f)

__device__ inline u16 f2bf(float f) {
  u32 u = __builtin_bit_cast(u32, f);
  u += 0x7FFF + ((u >> 16) & 1);   // round-to-nearest-even
  return (u16)(u >> 16);
}

__device__ inline u32 cvt_pk_bf16(float lo, float hi) {
  u32 d;
  asm("v_cvt_pk_bf16_f32 %0, %1, %2" : "=v"(d) : "v"(lo), "v"(hi));
  return d;
}

__device__ inline void gload_lds16(const void* g, void* l) {
  __builtin_amdgcn_global_load_lds(
      (const __attribute__((address_space(1))) void*)g,
      (__attribute__((address_space(3))) void*)l,
      16, 0, 0);
}

// ---------------- elementwise f32 -> bf16 ----------------
__global__ void cvt_f32_bf16(const float* __restrict__ in, u16* __restrict__ out, int n4) {
  int i = blockIdx.x * blockDim.x + threadIdx.x;
  int st = gridDim.x * blockDim.x;
  for (; i < n4; i += st) {
    float4 v = reinterpret_cast<const float4*>(in)[i];
    ushort4 o;
    o.x = f2bf(v.x); o.y = f2bf(v.y); o.z = f2bf(v.z); o.w = f2bf(v.w);
    reinterpret_cast<ushort4*>(out)[i] = o;
  }
}

// ---------------- NT GEMM: C[n,m] = sum_k A[n,k]*B[m,k] + bias[m] ----------------
// 128x128 tile, BK=32, 4 waves, TRIPLE-buffered counted-vmcnt pipeline,
// BRANCH-FREE tail: steady loop kt in [0, NT-2), then straight-line epilogue
// with vmcnt(4) / vmcnt(0) (the R4 tail race fix, no in-loop branches).
// Swizzle: 16B-chunk ^= (row>>1)&3 on GLOBAL SOURCE (linear LDS dest) and on
// ds_read addresses -> conflict-free quarter-wave reads.
template<bool OUT_BF16, bool WRITE_VT>
__global__ __launch_bounds__(256, 3) void gemm_nt(
    const u16* __restrict__ A, const u16* __restrict__ Bm,
    const float* __restrict__ bias, void* __restrict__ Cout,
    u16* __restrict__ vT, int K, int Mcols)
{
  __shared__ __align__(16) u16 sbuf[3][8192];   // [buf]{A:4096, B:4096} = 16KB x3
  const int tid = threadIdx.x;
  const int w = tid >> 6, l = tid & 63;
  const int wm = w >> 1, wn = w & 1;
  const int rl = l & 15, gl = l >> 4;
  const int rowBase = blockIdx.x * 128;
  const int colBase = blockIdx.y * 128;

  // staging geometry: thread covers LDS row rT (+64 on 2nd load), 16B-chunk t4;
  // source column is the inverse-swizzled chunk.
  const int rT = tid >> 2;
  const int t4 = tid & 3;
  const int cswE = (t4 * 8) ^ (((rT >> 1) & 3) << 3);   // u16 element offset in row
  const u16* aSrc0 = A  + (size_t)(rowBase + rT) * K + cswE;
  const u16* bSrc0 = Bm + (size_t)(colBase + rT) * K + cswE;
  const size_t rowSk = (size_t)64 * K;

  auto STAGE = [&](int kt) {
    u16* base = &sbuf[kt % 3][0];
    const int k0 = kt * 32;
    gload_lds16(aSrc0 + k0,         base + (size_t)tid * 8);
    gload_lds16(aSrc0 + rowSk + k0, base + 2048 + (size_t)tid * 8);
    gload_lds16(bSrc0 + k0,         base + 4096 + (size_t)tid * 8);
    gload_lds16(bSrc0 + rowSk + k0, base + 4096 + 2048 + (size_t)tid * 8);
  };

  // ds_read element offsets (per-lane constant across iterations)
  int aOff[4], bOff[4];
#pragma unroll
  for (int f = 0; f < 4; ++f) {
    int ra = wm * 64 + f * 16 + rl;
    aOff[f] = ra * 32 + ((gl * 8) ^ (((ra >> 1) & 3) << 3));
    int rb = wn * 64 + f * 16 + rl;
    bOff[f] = 4096 + rb * 32 + ((gl * 8) ^ (((rb >> 1) & 3) << 3));
  }

  f32x4 acc[4][4] = {};

  // body: barrier -> ds_read buf[kt%3] -> lgkmcnt(0) -> barrier -> 16 MFMA
#define GEMM_BODY(KT)                                                          \
  {                                                                            \
    __builtin_amdgcn_sched_barrier(0);                                         \
    __builtin_amdgcn_s_barrier();                                              \
    const u16* base = &sbuf[(KT) % 3][0];                                      \
    bf16x8 af[4], bf[4];                                                       \
    _Pragma("unroll")                                                          \
    for (int f = 0; f < 4; ++f) af[f] = *(const bf16x8*)(base + aOff[f]);      \
    _Pragma("unroll")                                                          \
    for (int f = 0; f < 4; ++f) bf[f] = *(const bf16x8*)(base + bOff[f]);      \
    asm volatile("s_waitcnt lgkmcnt(0)" ::: "memory");                         \
    __builtin_amdgcn_sched_barrier(0);                                         \
    __builtin_amdgcn_s_barrier();                                              \
    __builtin_amdgcn_s_setprio(1);                                             \
    _Pragma("unroll")                                                          \
    for (int fm = 0; fm < 4; ++fm)                                             \
      _Pragma("unroll")                                                        \
      for (int fn = 0; fn < 4; ++fn)                                           \
        acc[fm][fn] = __builtin_amdgcn_mfma_f32_16x16x32_bf16(af[fm], bf[fn],  \
                                                              acc[fm][fn], 0, 0, 0); \
    __builtin_amdgcn_s_setprio(0);                                             \
  }

  const int NT = K >> 5;          // 64 for K=2048
  STAGE(0);
  STAGE(1);

  for (int kt = 0; kt < NT - 2; ++kt) {
    STAGE(kt + 2);
    asm volatile("s_waitcnt vmcnt(8)" ::: "memory");   // 12 in flight -> tile kt done
    GEMM_BODY(kt);
  }
  // kt = NT-2: 8 loads outstanding -> wait to 4 (tile NT-2 resident)
  asm volatile("s_waitcnt vmcnt(4)" ::: "memory");
  GEMM_BODY(NT - 2);
  // kt = NT-1: 4 outstanding -> drain
  asm volatile("s_waitcnt vmcnt(0)" ::: "memory");
  GEMM_BODY(NT - 1);
#undef GEMM_BODY

  float bv[4];
#pragma unroll
  for (int fn = 0; fn < 4; ++fn) bv[fn] = bias[colBase + wn*64 + fn*16 + rl];

#pragma unroll
  for (int fm = 0; fm < 4; ++fm) {
#pragma unroll
    for (int fn = 0; fn < 4; ++fn) {
      const int col = colBase + wn*64 + fn*16 + rl;
#pragma unroll
      for (int r = 0; r < 4; ++r) {
        const int row = rowBase + wm*64 + fm*16 + gl*4 + r;
        float v = acc[fm][fn][r] + bv[fn];
        if (WRITE_VT && col >= DIM + HD) {   // V columns: also store V^T[b][d][t]
          int d = col - (DIM + HD);
          int b = row >> 10, t = row & 1023;
          vT[((size_t)(b*HD + d) << 10) + t] = f2bf(v);
        }
        float vs = (WRITE_VT && col < DIM) ? v * QSCALE_LOG2E : v;  // pre-scale Q
        if (OUT_BF16) ((u16*)Cout)[(size_t)row*Mcols + col] = f2bf(vs);
        else          ((float*)Cout)[(size_t)row*Mcols + col] = vs;
      }
    }
  }
}

// ---------------- causal MQA flash attention ----------------
// grid: (T/128, B*H). 8 waves x 16 q-rows = 128 q-rows/block. KV tile = 64, dbuf.
__global__ __launch_bounds__(512, 4) void mqa_attn(
    const u16* __restrict__ qkv, const u16* __restrict__ vT,
    u16* __restrict__ attout)
{
  // [buf] { K: 64s x 128d bf16 (16KB, XOR-swizzled) | V^T: 128d x 64s bf16 (16KB, swizzled) }
  __shared__ char lds[65536];

  const int tid = threadIdx.x;
  const int wid = tid >> 6, l = tid & 63;
  const int rl = l & 15, gl = l >> 4;
  const int qb = (int)gridDim.x - 1 - (int)blockIdx.x;  // heavy blocks dispatch first
  const int b = blockIdx.y >> 4, h = blockIdx.y & 15;
  const int qrow0 = qb*128 + wid*16;
  const int diag = qrow0 >> 6;     // this wave's diagonal KV-tile index
  const int itmax = 2*qb + 1;

  const u16* kbase = qkv + (size_t)b*TT*QKVD + DIM;
  const u16* vbase = vT + ((size_t)b*HD << 10);

  auto STAGE = [&](int buf, int s0) {
    char* kl = lds + buf*32768;
    char* vl = kl + 16384;
#pragma unroll
    for (int i = 0; i < 2; ++i) {
      int L = (i*8 + wid)*1024 + l*16;
      int s = L >> 8, kb = (L & 255) ^ ((s & 7) << 4);
      gload_lds16(kbase + (size_t)(s0 + s)*QKVD + (kb >> 1), kl + (i*8 + wid)*1024);
      int d = L >> 7, sb = (L & 127) ^ ((d & 7) << 4);
      gload_lds16(vbase + ((size_t)d << 10) + s0 + (sb >> 1), vl + (i*8 + wid)*1024);
    }
  };

  STAGE(0, 0);
  asm volatile("" ::: "memory");

  // Q fragments (B-operand: col=t=rl, k=d); Q already scaled by 1/sqrt(hd)*log2e
  bf16x8 qf[4];
  {
    const u16* qp = qkv + (size_t)(b*TT + qrow0 + rl)*QKVD + h*HD + gl*8;
#pragma unroll
    for (int kk = 0; kk < 4; ++kk) qf[kk] = *(const bf16x8*)(qp + kk*32);
  }

  f32x4 accO[8] = {};
  float mrow = -INFINITY, lrow = 0.f;
  const int tg = qrow0 + rl;                         // this lane's q-row
  const int addrA = (((gl & 1) * 2) * 16 + rl) * 4;  // bpermute byte addrs
  const int addrB = addrA + 64;
  const bool hiSel = (gl >= 2);

  for (int it = 0; it <= itmax; ++it) {
    if (it < itmax) {
      STAGE((it + 1) & 1, (it + 1) << 6);
      asm volatile("s_waitcnt vmcnt(4)" ::: "memory");  // current tile done, next in flight
    } else {
      asm volatile("s_waitcnt vmcnt(0)" ::: "memory");
    }
    __builtin_amdgcn_s_barrier();

    if (it <= diag) {   // wave-uniform: skip fully-future tiles (still stage+barrier)
      const char* kl = lds + (it & 1)*32768;
      const char* vl = kl + 16384;

      // S^T = mfma(K, Q): sc[fs][r] = S^T[s = fs*16 + gl*4 + r][t = rl], exp2 domain
      f32x4 sc[4] = {};
      __builtin_amdgcn_s_setprio(1);
#pragma unroll
      for (int fs = 0; fs < 4; ++fs) {
        const int s = fs*16 + rl;
#pragma unroll
        for (int kkd = 0; kkd < 4; ++kkd) {
          bf16x8 kf = *(const bf16x8*)(kl + ((s*256 + kkd*64 + gl*16) ^ ((s & 7) << 4)));
          sc[fs] = __builtin_amdgcn_mfma_f32_16x16x32_bf16(kf, qf[kkd], sc[fs], 0, 0, 0);
        }
      }
      __builtin_amdgcn_s_setprio(0);

      // causal mask only on the diagonal tile (wave-uniform branch)
      if (it == diag) {
        const int s0 = it << 6;
#pragma unroll
        for (int fs = 0; fs < 4; ++fs)
#pragma unroll
          for (int r = 0; r < 4; ++r) {
            int sg = s0 + fs*16 + gl*4 + r;
            if (sg > tg) sc[fs][r] = -INFINITY;
          }
      }

      // tile max (depth-4 tree + 2 shfl)
      float mx = -INFINITY;
#pragma unroll
      for (int fs = 0; fs < 4; ++fs)
        mx = fmaxf(mx, fmaxf(fmaxf(sc[fs][0], sc[fs][1]), fmaxf(sc[fs][2], sc[fs][3])));
      mx = fmaxf(mx, __shfl_xor(mx, 16));
      mx = fmaxf(mx, __shfl_xor(mx, 32));

      // defer-max: rescale only if max grew by > 8 (exp2 domain -> P <= 256)
      if (!__all(mx <= mrow + 8.f)) {
        float mnew = fmaxf(mrow, mx);
        float rr = __builtin_amdgcn_exp2f(mrow - mnew);
#pragma unroll
        for (int fd = 0; fd < 8; ++fd)
#pragma unroll
          for (int r = 0; r < 4; ++r) accO[fd][r] *= rr;
        lrow *= rr;
        mrow = mnew;
      }

      float ps = 0.f;
#pragma unroll
      for (int fs = 0; fs < 4; ++fs)
#pragma unroll
        for (int r = 0; r < 4; ++r) {
          float p = __builtin_amdgcn_exp2f(sc[fs][r] - mrow);
          sc[fs][r] = p;
          ps += p;
        }
      ps += __shfl_xor(ps, 16);
      ps += __shfl_xor(ps, 32);
      lrow += ps;

      // pack P^T to bf16 pairs, redistribute into PV B-fragments via bpermute
      u32 pw[4][2];
#pragma unroll
      for (int fs = 0; fs < 4; ++fs) {
        pw[fs][0] = cvt_pk_bf16(sc[fs][0], sc[fs][1]);
        pw[fs][1] = cvt_pk_bf16(sc[fs][2], sc[fs][3]);
      }
      u32x4 bw[2];
#pragma unroll
      for (int kk = 0; kk < 2; ++kk)
#pragma unroll
        for (int w = 0; w < 4; ++w) {
          int addr = (w < 2) ? addrA : addrB;
          u32 lo = __builtin_amdgcn_ds_bpermute(addr, (int)pw[2*kk + 0][w & 1]);
          u32 hi = __builtin_amdgcn_ds_bpermute(addr, (int)pw[2*kk + 1][w & 1]);
          bw[kk][w] = hiSel ? hi : lo;
        }

      // O^T += V^T * P^T : accO[fd][r] = O^T[d = fd*16 + gl*4 + r][t = rl]
      __builtin_amdgcn_s_setprio(1);
#pragma unroll
      for (int kk = 0; kk < 2; ++kk) {
        bf16x8 pb = __builtin_bit_cast(bf16x8, bw[kk]);
#pragma unroll
        for (int fd = 0; fd < 8; ++fd) {
          const int d = fd*16 + rl;
          bf16x8 vf = *(const bf16x8*)(vl + ((d*128 + kk*64 + gl*16) ^ ((d & 7) << 4)));
          accO[fd] = __builtin_amdgcn_mfma_f32_16x16x32_bf16(vf, pb, accO[fd], 0, 0, 0);
        }
      }
      __builtin_amdgcn_s_setprio(0);
    }

    __builtin_amdgcn_s_barrier();   // all waves done reading buf[it&1] before overwrite
  }

  const float inv = 1.0f / lrow;
  u16* outp = attout + (size_t)(b*TT + tg)*DIM + h*HD;
#pragma unroll
  for (int fd = 0; fd < 8; ++fd) {
    ushort4 o;
    o.x = f2bf(accO[fd][0] * inv);
    o.y = f2bf(accO[fd][1] * inv);
    o.z = f2bf(accO[fd][2] * inv);
    o.w = f2bf(accO[fd][3] * inv);
    *(ushort4*)(outp + fd*16 + gl*4) = o;
  }
}

// ---------------- launch ----------------
extern "C" void kernel_launch(void* const* d_in, const int* in_sizes, int n_in,
                              void* d_out, int out_size, void* d_ws, size_t ws_size,
                              hipStream_t stream) {
  const float* x    = (const float*)d_in[0];
  const float* Wqkv = (const float*)d_in[1];
  const float* bqkv = (const float*)d_in[2];
  const float* Wout = (const float*)d_in[3];
  const float* bout = (const float*)d_in[4];

  char* ws = (char*)d_ws;
  u16* xb    = (u16*)(ws);
  u16* wqb   = (u16*)(ws + 33554432);
  u16* qkvb  = (u16*)(ws + 33554432 + 9437184);
  u16* vtb   = (u16*)(ws + 33554432 + 9437184 + 37748736);
  u16* attb  = xb;     // x_bf16 dead after GEMM1
  u16* woutb = wqb;    // Wqkv_bf16 dead after GEMM1

  cvt_f32_bf16<<<2048, 256, 0, stream>>>(x,    xb,  NROW*DIM/4);
  cvt_f32_bf16<<<2048, 256, 0, stream>>>(Wqkv, wqb, QKVD*DIM/4);

  dim3 g1(NROW/128, QKVD/128);
  gemm_nt<true, true><<<g1, 256, 0, stream>>>(xb, wqb, bqkv, qkvb, vtb, DIM, QKVD);

  cvt_f32_bf16<<<2048, 256, 0, stream>>>(Wout, woutb, DIM*DIM/4);

  dim3 ga(TT/128, BB*NH);
  mqa_attn<<<ga, 512, 0, stream>>>(qkvb, vtb, attb);

  dim3 g2(NROW/128, DIM/128);
  gemm_nt<false, false><<<g2, 256, 0, stream>>>(attb, woutb, bout, d_out, nullptr, DIM, DIM);
}